// Round 5
// baseline (913.026 us; speedup 1.0000x reference)
//
#include <hip/hip_runtime.h>
#include <hip/hip_bf16.h>

typedef __bf16  bf16x8 __attribute__((ext_vector_type(8)));
typedef float   f32x4  __attribute__((ext_vector_type(4)));
typedef __hip_bfloat16 bf;

// clamp + NaN-sanitize (fmaxf/fminf return the non-NaN operand on AMD)
__device__ __forceinline__ float clamp256(float v) {
    return fminf(fmaxf(v, -256.f), 256.f);
}
__device__ __forceinline__ float sane(float v) {
    return fminf(fmaxf(v, -1e4f), 1e4f);
}

// ---------------------------------------------------------------------------
// 64x64-tile bf16 MFMA GEMM. C[M][N] = sum_taps A_shift[M][K] * Wt[tap][N][K]^T
// Optional fused residual 1x1 conv Wd[N][K] -> second accumulator.
// mode 0: store (+bias f32, opt relu) -> bf16 (outb) or f32 (outf)
// mode 2: LayerNorm(nn over l) + relu + residual (accR+biasd if Wd else res[]),
//         bf16 store, zero rows [nn,32). padded=1: A rows are (graph,l), L_PAD=32.
// ---------------------------------------------------------------------------
__global__ __launch_bounds__(256) void gemm_kernel(
    const bf* __restrict__ A, const bf* __restrict__ Wt, const bf* __restrict__ Wd,
    const float* __restrict__ bias, const float* __restrict__ biasd,
    const float* __restrict__ lnw, const float* __restrict__ lnb,
    const bf* __restrict__ res, int res_stride,
    bf* __restrict__ outb, float* __restrict__ outf, int out_stride,
    int M, int N, int K, int taps, int dil,
    int mode, int relu, int padded, int nn)
{
    __shared__ __align__(16) unsigned short sA[64 * 40];
    __shared__ __align__(16) unsigned short sB[64 * 40];
    __shared__ float sOc[64 * 66];
    __shared__ float sOr[64 * 66];

    const int tid  = threadIdx.x;
    const int wv   = tid >> 6;
    const int lane = tid & 63;
    const int m0   = blockIdx.y * 64;
    const int n0   = blockIdx.x * 64;

    f32x4 accC[4], accR[4];
    #pragma unroll
    for (int i = 0; i < 4; ++i) { accC[i] = 0.f; accR[i] = 0.f; }

    const int arow = tid >> 2;           // staging row 0..63
    const int achk = (tid & 3) << 3;     // staging col chunk (bf16 elems)
    const int frow = lane & 15;
    const int fq   = lane >> 4;
    const int a_off = (wv * 16 + frow) * 40 + fq * 8;

    const int ntap = taps + (Wd ? 1 : 0);
    for (int tap = 0; tap < ntap; ++tap) {
        const bool isRes = (tap >= taps);
        const int shift = isRes ? 0 : (tap - (taps >> 1)) * dil;
        const bf* Wtap = isRes ? Wd : (Wt + (size_t)tap * N * K);
        int ra;
        if (padded) {
            int token = m0 + arow;
            int b = token >> 5, l = token & 31;
            int ls = l + shift;
            ra = ((unsigned)ls < (unsigned)nn) ? (b * 32 + ls) : -1;
            if (token >= M) ra = -1;
        } else {
            int rg = m0 + arow;
            ra = (rg < M) ? rg : -1;
        }
        const int rb = n0 + arow;
        const bool bval = rb < N;

        for (int kb = 0; kb < K; kb += 32) {
            __syncthreads();
            uint4 va = make_uint4(0u, 0u, 0u, 0u);
            if (ra >= 0) va = *(const uint4*)(A + (size_t)ra * K + kb + achk);
            uint4 vb = make_uint4(0u, 0u, 0u, 0u);
            if (bval)   vb = *(const uint4*)(Wtap + (size_t)rb * K + kb + achk);
            *(uint4*)(sA + arow * 40 + achk) = va;
            *(uint4*)(sB + arow * 40 + achk) = vb;
            __syncthreads();
            bf16x8 af = *(const bf16x8*)(sA + a_off);
            if (isRes) {
                #pragma unroll
                for (int nt = 0; nt < 4; ++nt) {
                    bf16x8 bfg = *(const bf16x8*)(sB + (nt * 16 + frow) * 40 + fq * 8);
                    accR[nt] = __builtin_amdgcn_mfma_f32_16x16x32_bf16(af, bfg, accR[nt], 0, 0, 0);
                }
            } else {
                #pragma unroll
                for (int nt = 0; nt < 4; ++nt) {
                    bf16x8 bfg = *(const bf16x8*)(sB + (nt * 16 + frow) * 40 + fq * 8);
                    accC[nt] = __builtin_amdgcn_mfma_f32_16x16x32_bf16(af, bfg, accC[nt], 0, 0, 0);
                }
            }
        }
    }

    if (mode == 0) {
        #pragma unroll
        for (int nt = 0; nt < 4; ++nt) {
            int col = n0 + nt * 16 + frow;
            if (col >= N) continue;
            float bv = bias ? bias[col] : 0.f;
            #pragma unroll
            for (int r = 0; r < 4; ++r) {
                int row = m0 + wv * 16 + fq * 4 + r;
                if (row >= M) continue;
                float v = accC[nt][r] + bv;
                if (relu) v = fmaxf(v, 0.f);
                if (outb) outb[(size_t)row * out_stride + col] = __float2bfloat16(clamp256(v));
                else      outf[(size_t)row * out_stride + col] = sane(v);
            }
        }
    } else {  // mode 2: LN + relu + residual
        __syncthreads();
        #pragma unroll
        for (int nt = 0; nt < 4; ++nt)
            #pragma unroll
            for (int r = 0; r < 4; ++r)
                sOc[(wv * 16 + fq * 4 + r) * 66 + nt * 16 + frow] = accC[nt][r];
        if (Wd) {
            #pragma unroll
            for (int nt = 0; nt < 4; ++nt)
                #pragma unroll
                for (int r = 0; r < 4; ++r)
                    sOr[(wv * 16 + fq * 4 + r) * 66 + nt * 16 + frow] = accR[nt][r];
        }
        __syncthreads();
        if (tid < 128) {
            int gi = tid >> 6, col = tid & 63;
            int colg = n0 + col;
            if (colg < N) {
                float bv = bias[colg];
                float bd = (Wd && biasd) ? biasd[colg] : 0.f;
                float xv[32]; float s = 0.f, s2 = 0.f;
                for (int l = 0; l < nn; ++l) {
                    float v = sane(sOc[(gi * 32 + l) * 66 + col] + bv);
                    xv[l] = v; s += v; s2 += v * v;
                }
                float inv = 1.f / (float)nn;
                float mu = s * inv;
                float var = s2 * inv - mu * mu;
                float rs = rsqrtf(fmaxf(var, 0.f) + 1e-5f);
                int tokbase = m0 + gi * 32;
                for (int l = 0; l < nn; ++l) {
                    float v = (xv[l] - mu) * rs * lnw[l] + lnb[l];
                    v = fmaxf(v, 0.f);
                    float rr = Wd ? sane(sOr[(gi * 32 + l) * 66 + col] + bd)
                                  : __bfloat162float(res[(size_t)(tokbase + l) * res_stride + colg]);
                    outb[(size_t)(tokbase + l) * out_stride + colg] = __float2bfloat16(clamp256(v + rr));
                }
                for (int l = nn; l < 32; ++l)
                    outb[(size_t)(tokbase + l) * out_stride + colg] = __float2bfloat16(0.f);
            }
        }
    }
}

// ---------------------------------------------------------------------------
// GAT edge scores: wave per edge; expe f32 in ws; f32 atomic denominator.
// ---------------------------------------------------------------------------
__global__ __launch_bounds__(256) void edge_kernel(
    const int* __restrict__ ei, const bf* __restrict__ xlb, const bf* __restrict__ xrb,
    const float* __restrict__ att, float* __restrict__ expe, float* __restrict__ nsum,
    int E0, int ET, int NN)
{
    int e = blockIdx.x * 4 + (threadIdx.x >> 6);
    if (e >= ET) return;
    int lane = threadIdx.x & 63;
    int src, dst;
    if (e < E0) { src = ei[e]; dst = ei[E0 + e]; }
    else        { src = dst = e - E0; }
    src = min(max(src, 0), NN - 1);
    dst = min(max(dst, 0), NN - 1);
    const bf* xls = xlb + (size_t)src * 256;
    const bf* xrd = xrb + (size_t)dst * 256;
    float s[4];
    #pragma unroll
    for (int h = 0; h < 4; ++h) {
        float v = __bfloat162float(xls[h * 64 + lane]) + __bfloat162float(xrd[h * 64 + lane]);
        v = v > 0.f ? v : 0.2f * v;
        s[h] = v * att[h * 64 + lane];
    }
    #pragma unroll
    for (int h = 0; h < 4; ++h)
        #pragma unroll
        for (int off = 32; off > 0; off >>= 1) s[h] += __shfl_down(s[h], off);
    if (lane == 0) {
        #pragma unroll
        for (int h = 0; h < 4; ++h) {
            float sv = fminf(fmaxf(s[h], -60.f), 60.f);   // sanitizes NaN too
            float ex = __expf(sv);
            expe[(size_t)e * 4 + h] = ex;
            atomicAdd(&nsum[(size_t)dst * 4 + h], ex);
        }
    }
}

// ---------------------------------------------------------------------------
// Per-graph aggregation: column-private LDS accumulators (no atomics/syncs).
// ---------------------------------------------------------------------------
__global__ __launch_bounds__(256) void agg_kernel(
    const int* __restrict__ ei, const bf* __restrict__ xlb,
    const float* __restrict__ expe, const float* __restrict__ nsum,
    const float* __restrict__ gbias, bf* __restrict__ hbuf,
    int E0, int EPG, int NN, int nn)
{
    __shared__ float accS[32 * 256];
    int g = blockIdx.x, ch = threadIdx.x, h = ch >> 6;
    for (int l = 0; l < nn; ++l) accS[l * 256 + ch] = 0.f;
    for (int j = 0; j < EPG; ++j) {
        int e = g * EPG + j;
        int src = min(max(ei[e], 0), NN - 1);
        int dst = min(max(ei[E0 + e], 0), NN - 1);
        int dl = min(max(dst - g * nn, 0), nn - 1);
        float al = expe[(size_t)e * 4 + h] / fmaxf(nsum[(size_t)dst * 4 + h], 1e-30f);
        al = fminf(fmaxf(al, 0.f), 1.f);
        accS[dl * 256 + ch] += al * __bfloat162float(xlb[(size_t)src * 256 + ch]);
    }
    for (int i = 0; i < nn; ++i) {
        int e = E0 + g * nn + i;
        int node = g * nn + i;
        float al = expe[(size_t)e * 4 + h] / fmaxf(nsum[(size_t)node * 4 + h], 1e-30f);
        al = fminf(fmaxf(al, 0.f), 1.f);
        accS[i * 256 + ch] += al * __bfloat162float(xlb[(size_t)node * 256 + ch]);
    }
    float bv = gbias[ch];
    for (int l = 0; l < nn; ++l) {
        float v = fmaxf(accS[l * 256 + ch] + bv, 0.f);
        hbuf[((size_t)g * 32 + l) * 256 + ch] = __float2bfloat16(clamp256(v));
    }
    for (int l = nn; l < 32; ++l)
        hbuf[((size_t)g * 32 + l) * 256 + ch] = __float2bfloat16(0.f);
}

// ---------------------------------------------------------------------------
// LAST kernel: alpha = expe/nsum (f32) and ei (f32 of exact indices).
// ---------------------------------------------------------------------------
__global__ __launch_bounds__(256) void alpha_ei_kernel(
    const int* __restrict__ ei, const float* __restrict__ expe,
    const float* __restrict__ nsum,
    float* __restrict__ dalpha, float* __restrict__ dei, int E0, int ET, int NN)
{
    int e = blockIdx.x * 256 + threadIdx.x;
    if (e >= ET) return;
    int src, dst;
    if (e < E0) { src = ei[e]; dst = ei[E0 + e]; }
    else        { src = dst = e - E0; }
    src = min(max(src, 0), NN - 1);
    dst = min(max(dst, 0), NN - 1);
    #pragma unroll
    for (int h = 0; h < 4; ++h) {
        float al = expe[(size_t)e * 4 + h] / fmaxf(nsum[(size_t)dst * 4 + h], 1e-30f);
        dalpha[(size_t)e * 4 + h] = fminf(fmaxf(al, 0.f), 1.f);
    }
    dei[e]              = (float)src;
    dei[(size_t)ET + e] = (float)dst;
}

// f32 -> bf16 bulk convert
__global__ void cvt_bf16(const float* __restrict__ in, bf* __restrict__ o, int n)
{
    int i = blockIdx.x * 256 + threadIdx.x;
    if (i < n) o[i] = __float2bfloat16(in[i]);
}

// Weight prep: f32 [Co][Ci][3] -> bf16 [3][Co][Ci]
__global__ void prep_taps(const float* __restrict__ w, bf* __restrict__ o, int Co, int Ci)
{
    int idx = blockIdx.x * 256 + threadIdx.x;
    if (idx >= Co * Ci) return;
    #pragma unroll
    for (int k = 0; k < 3; ++k)
        o[(size_t)k * Co * Ci + idx] = __float2bfloat16(w[(size_t)idx * 3 + k]);
}

// fc1_w f32 [F1][ci*nn+l] -> bf16 W1t [F1][l*256+ci], l padded to 32 with zeros
__global__ void prep_fc1(const float* __restrict__ w, bf* __restrict__ o, int F1, int nn)
{
    int idx = blockIdx.x * 256 + threadIdx.x;
    if (idx >= F1 * 8192) return;
    int co = idx >> 13, r = idx & 8191, l = r >> 8, ci = r & 255;
    float hv = 0.f;
    if (l < nn) hv = w[(size_t)co * (256 * nn) + ci * nn + l];
    o[idx] = __float2bfloat16(hv);
}

extern "C" void kernel_launch(void* const* d_in, const int* in_sizes, int n_in,
                              void* d_out, int out_size, void* d_ws, size_t ws_size,
                              hipStream_t stream)
{
    (void)n_in; (void)ws_size;
    // ALL float inputs are FLOAT32 (reference setup_inputs dtype); edge_index int32.
    const float* x   = (const float*)d_in[0];
    const float* Wl  = (const float*)d_in[1];  const float* bl  = (const float*)d_in[2];
    const float* Wr  = (const float*)d_in[3];  const float* br  = (const float*)d_in[4];
    const float* att = (const float*)d_in[5];  const float* gb  = (const float*)d_in[6];
    const float* t0w = (const float*)d_in[7];  const float* t0b = (const float*)d_in[8];
    const float* l0w = (const float*)d_in[9];  const float* l0b = (const float*)d_in[10];
    const float* t1w = (const float*)d_in[11]; const float* t1b = (const float*)d_in[12];
    const float* l1w = (const float*)d_in[13]; const float* l1b = (const float*)d_in[14];
    const float* d1w = (const float*)d_in[15]; const float* d1b = (const float*)d_in[16];
    const float* t2w = (const float*)d_in[17]; const float* t2b = (const float*)d_in[18];
    const float* l2w = (const float*)d_in[19]; const float* l2b = (const float*)d_in[20];
    const float* d2w = (const float*)d_in[21]; const float* d2b = (const float*)d_in[22];
    const float* f1w = (const float*)d_in[23]; const float* f1b = (const float*)d_in[24];
    const float* f2w = (const float*)d_in[25]; const float* f2b = (const float*)d_in[26];
    const float* f3w = (const float*)d_in[27]; const float* f3b = (const float*)d_in[28];
    const int*   ei  = (const int*)d_in[29];

    // ---- Runtime-derived shapes ----
    const int HC   = in_sizes[6];                        // 256
    const int F_IN = in_sizes[1] / (HC > 0 ? HC : 1);    // 64
    const int NN   = in_sizes[0] / (F_IN > 0 ? F_IN : 1);// 30720 nodes
    const int E0   = in_sizes[29] / 2;                   // 245760
    const int ET   = E0 + NN;                            // 276480
    int nn = in_sizes[9];  nn = nn < 1 ? 1 : (nn > 32 ? 32 : nn);  // 30
    const int NG   = NN / nn;                            // 1024
    const int EPG  = NG > 0 ? E0 / NG : 0;               // 240
    const int C1   = in_sizes[12];                       // 512
    const int C2   = in_sizes[18];                       // 256
    const int F1   = in_sizes[24];                       // 512
    const int F2   = in_sizes[26];                       // 256
    const int F3   = in_sizes[28];                       // 144
    const int NG2  = (NG + 1) / 2;

    // ---- Output layout (FLOAT32 elements), ei anchored at the end ----
    float* dout   = (float*)d_out;
    float* dei    = dout + ((size_t)out_size - 2 * (size_t)ET);
    float* dalpha = dei - (size_t)ET * 4;

    // ---- Workspace (peak ~40.5 MiB) ----
    char* ws = (char*)d_ws;
    const size_t MB = 1ull << 20;
    float* nsum = (float*)(ws);                               // [0, 0.5M)
    bf*    xb   = (bf*)(ws + 524288);                         // x bf16, 3.93M
    float* expe = (float*)(ws + 524288);                      // AFTER GAT GEMMs, 4.42M
    bf*    WkA  = (bf*)(ws + 5 * MB);                         // 3*HC*HC bf16
    bf*    WkB  = WkA + (size_t)3 * HC * HC;                  // 3*C1*HC
    bf*    WkC  = WkB + (size_t)3 * C1 * HC;                  // 3*C2*C1
    bf*    Wlb  = WkC + (size_t)3 * C2 * C1;
    bf*    Wrb  = Wlb + (size_t)HC * F_IN;
    bf*    f2wb = Wrb + (size_t)HC * F_IN;
    bf*    f3wb = f2wb + (size_t)F2 * F1;
    bf*    d1wb = f3wb + (size_t)F3 * F2;
    bf*    d2wb = d1wb + (size_t)C1 * HC;                     // ends < 8.5M
    const size_t S0 = (size_t)(8.5 * MB);
    const size_t S1 = S0 + 16 * MB;                           // total 40.5M
    bf*    xrb  = (bf*)(ws + S0);
    bf*    hbuf = (bf*)(ws + S0);
    bf*    y1c  = (bf*)(ws + S0);
    bf*    W1t  = (bf*)(ws + S0);
    bf*    z1   = (bf*)(ws + S0 + 9 * MB);
    bf*    z2   = (bf*)(ws + S0 + 11 * MB);
    bf*    xlb  = (bf*)(ws + S1);
    bf*    y0   = (bf*)(ws + S1);
    bf*    y2   = (bf*)(ws + S1);

    hipMemsetAsync(nsum, 0, (size_t)NN * 4 * sizeof(float), stream);

    // ---- Convert weights/inputs to bf16 ----
    cvt_bf16<<<(NN * F_IN + 255) / 256, 256, 0, stream>>>(x, xb, NN * F_IN);
    cvt_bf16<<<(HC * F_IN + 255) / 256, 256, 0, stream>>>(Wl, Wlb, HC * F_IN);
    cvt_bf16<<<(HC * F_IN + 255) / 256, 256, 0, stream>>>(Wr, Wrb, HC * F_IN);
    cvt_bf16<<<(F2 * F1 + 255) / 256, 256, 0, stream>>>(f2w, f2wb, F2 * F1);
    cvt_bf16<<<(F3 * F2 + 255) / 256, 256, 0, stream>>>(f3w, f3wb, F3 * F2);
    cvt_bf16<<<(C1 * HC + 255) / 256, 256, 0, stream>>>(d1w, d1wb, C1 * HC);
    cvt_bf16<<<(C2 * C1 + 255) / 256, 256, 0, stream>>>(d2w, d2wb, C2 * C1);
    prep_taps<<<(HC * HC + 255) / 256, 256, 0, stream>>>(t0w, WkA, HC, HC);
    prep_taps<<<(C1 * HC + 255) / 256, 256, 0, stream>>>(t1w, WkB, C1, HC);
    prep_taps<<<(C2 * C1 + 255) / 256, 256, 0, stream>>>(t2w, WkC, C2, C1);

    // ---- GAT linear transforms (bf16 out) ----
    gemm_kernel<<<dim3((HC + 63) / 64, (NN + 63) / 64), 256, 0, stream>>>(
        xb, Wlb, nullptr, bl, nullptr, nullptr, nullptr, nullptr, 0,
        xlb, nullptr, HC, NN, HC, F_IN, 1, 1, 0, 0, 0, nn);
    gemm_kernel<<<dim3((HC + 63) / 64, (NN + 63) / 64), 256, 0, stream>>>(
        xb, Wrb, nullptr, br, nullptr, nullptr, nullptr, nullptr, 0,
        xrb, nullptr, HC, NN, HC, F_IN, 1, 1, 0, 0, 0, nn);

    // ---- Edge scores + aggregation ----
    edge_kernel<<<(ET + 3) / 4, 256, 0, stream>>>(ei, xlb, xrb, att, expe, nsum, E0, ET, NN);
    agg_kernel<<<NG, 256, 0, stream>>>(ei, xlb, expe, nsum, gb, hbuf, E0, EPG, NN, nn);

    // ---- TCN block 0 (full): conv(d=1) -> LN -> relu -> + h ----
    gemm_kernel<<<dim3((HC + 63) / 64, NG * 32 / 64), 256, 0, stream>>>(
        hbuf, WkA, nullptr, t0b, nullptr, l0w, l0b, hbuf, HC,
        y0, nullptr, HC, NG * 32, HC, HC, 3, 1, 2, 0, 1, nn);

    // ---- TCN blocks 1 & 2, two graph-chunks; y2 in place over y0 ----
    for (int c = 0; c < 2; ++c) {
        int g0 = c * NG2;
        int gc = (c == 0) ? NG2 : (NG - NG2);
        if (gc <= 0) continue;
        const bf* y0c = y0 + (size_t)g0 * 32 * HC;
        bf*       y2c = y0 + (size_t)g0 * 32 * HC;
        gemm_kernel<<<dim3((C1 + 63) / 64, gc * 32 / 64), 256, 0, stream>>>(
            y0c, WkB, d1wb, t1b, d1b, l1w, l1b, nullptr, 0,
            y1c, nullptr, C1, gc * 32, C1, HC, 3, 2, 2, 0, 1, nn);
        gemm_kernel<<<dim3((C2 + 63) / 64, gc * 32 / 64), 256, 0, stream>>>(
            y1c, WkC, d2wb, t2b, d2b, l2w, l2b, nullptr, 0,
            y2c, nullptr, C2, gc * 32, C2, C1, 3, 4, 2, 0, 1, nn);
    }

    // ---- FC head (W1t overwrites dead y1c) ----
    prep_fc1<<<(F1 * 8192 + 255) / 256, 256, 0, stream>>>(f1w, W1t, F1, nn);
    gemm_kernel<<<dim3((F1 + 63) / 64, (NG + 63) / 64), 256, 0, stream>>>(
        y2, W1t, nullptr, f1b, nullptr, nullptr, nullptr, nullptr, 0,
        z1, nullptr, F1, NG, F1, 8192, 1, 1, 0, 1, 0, nn);
    gemm_kernel<<<dim3((F2 + 63) / 64, (NG + 63) / 64), 256, 0, stream>>>(
        z1, f2wb, nullptr, f2b, nullptr, nullptr, nullptr, nullptr, 0,
        z2, nullptr, F2, NG, F2, F1, 1, 1, 0, 1, 0, nn);
    gemm_kernel<<<dim3((F3 + 63) / 64, (NG + 63) / 64), 256, 0, stream>>>(
        z2, f3wb, nullptr, f3b, nullptr, nullptr, nullptr, nullptr, 0,
        nullptr, dout, F3, NG, F3, F2, 1, 1, 0, 0, 0, nn);

    // ---- LAST: alpha (f32) + ei (f32) ----
    alpha_ei_kernel<<<(ET + 255) / 256, 256, 0, stream>>>(
        ei, expe, nsum, dalpha, dei, E0, ET, NN);
}

// Round 6
// 785.978 us; speedup vs baseline: 1.1616x; 1.1616x over previous
//
#include <hip/hip_runtime.h>
#include <hip/hip_bf16.h>

typedef __bf16  bf16x8 __attribute__((ext_vector_type(8)));
typedef float   f32x4  __attribute__((ext_vector_type(4)));
typedef __hip_bfloat16 bf;

// clamp + NaN-sanitize (fmaxf/fminf return the non-NaN operand on AMD)
__device__ __forceinline__ float clamp256(float v) {
    return fminf(fmaxf(v, -256.f), 256.f);
}
__device__ __forceinline__ float sane(float v) {
    return fminf(fmaxf(v, -1e4f), 1e4f);
}

// ---------------------------------------------------------------------------
// 64x64-tile bf16 MFMA GEMM. C[M][N] = sum_taps A_shift[M][K] * Wt[tap][N][K]^T
// Optional fused residual 1x1 conv Wd[N][K] -> second accumulator (registers).
// mode 0: store (+bias f32, opt relu) -> bf16 (outb) or f32 (outf)
// mode 2: LayerNorm(nn over l) + relu + residual, computed ON the register
//         C-layout (no epilogue LDS transpose): per-column partial sums are
//         reduced over the fq quads via shfl_xor(16/32), then combined across
//         the 2 waves covering each 32-row graph through a 2 KB LDS buffer.
//         LDS total 12.3 KB/block (was 44 KB) -> ~2x occupancy.
// padded=1: A rows are (graph,l), L_PAD=32; tap shift masks l+s outside [0,nn)
// ---------------------------------------------------------------------------
__global__ __launch_bounds__(256) void gemm_kernel(
    const bf* __restrict__ A, const bf* __restrict__ Wt, const bf* __restrict__ Wd,
    const float* __restrict__ bias, const float* __restrict__ biasd,
    const float* __restrict__ lnw, const float* __restrict__ lnb,
    const bf* __restrict__ res, int res_stride,
    bf* __restrict__ outb, float* __restrict__ outf, int out_stride,
    int M, int N, int K, int taps, int dil,
    int mode, int relu, int padded, int nn)
{
    __shared__ __align__(16) unsigned short sA[64 * 40];
    __shared__ __align__(16) unsigned short sB[64 * 40];
    __shared__ float sS[4][64];    // per-wave 16-row column sums
    __shared__ float sS2[4][64];   // per-wave 16-row column sums of squares

    const int tid  = threadIdx.x;
    const int wv   = tid >> 6;
    const int lane = tid & 63;
    const int m0   = blockIdx.y * 64;
    const int n0   = blockIdx.x * 64;

    f32x4 accC[4], accR[4];
    #pragma unroll
    for (int i = 0; i < 4; ++i) { accC[i] = 0.f; accR[i] = 0.f; }

    const int arow = tid >> 2;           // staging row 0..63
    const int achk = (tid & 3) << 3;     // staging col chunk (bf16 elems)
    const int frow = lane & 15;
    const int fq   = lane >> 4;
    const int a_off = (wv * 16 + frow) * 40 + fq * 8;

    const int ntap = taps + (Wd ? 1 : 0);
    for (int tap = 0; tap < ntap; ++tap) {
        const bool isRes = (tap >= taps);
        const int shift = isRes ? 0 : (tap - (taps >> 1)) * dil;
        const bf* Wtap = isRes ? Wd : (Wt + (size_t)tap * N * K);
        int ra;
        if (padded) {
            int token = m0 + arow;
            int b = token >> 5, l = token & 31;
            int ls = l + shift;
            ra = ((unsigned)ls < (unsigned)nn) ? (b * 32 + ls) : -1;
            if (token >= M) ra = -1;
        } else {
            int rg = m0 + arow;
            ra = (rg < M) ? rg : -1;
        }
        const int rb = n0 + arow;
        const bool bval = rb < N;

        for (int kb = 0; kb < K; kb += 32) {
            __syncthreads();
            uint4 va = make_uint4(0u, 0u, 0u, 0u);
            if (ra >= 0) va = *(const uint4*)(A + (size_t)ra * K + kb + achk);
            uint4 vb = make_uint4(0u, 0u, 0u, 0u);
            if (bval)   vb = *(const uint4*)(Wtap + (size_t)rb * K + kb + achk);
            *(uint4*)(sA + arow * 40 + achk) = va;
            *(uint4*)(sB + arow * 40 + achk) = vb;
            __syncthreads();
            bf16x8 af = *(const bf16x8*)(sA + a_off);
            if (isRes) {
                #pragma unroll
                for (int nt = 0; nt < 4; ++nt) {
                    bf16x8 bfg = *(const bf16x8*)(sB + (nt * 16 + frow) * 40 + fq * 8);
                    accR[nt] = __builtin_amdgcn_mfma_f32_16x16x32_bf16(af, bfg, accR[nt], 0, 0, 0);
                }
            } else {
                #pragma unroll
                for (int nt = 0; nt < 4; ++nt) {
                    bf16x8 bfg = *(const bf16x8*)(sB + (nt * 16 + frow) * 40 + fq * 8);
                    accC[nt] = __builtin_amdgcn_mfma_f32_16x16x32_bf16(af, bfg, accC[nt], 0, 0, 0);
                }
            }
        }
    }

    if (mode == 0) {
        #pragma unroll
        for (int nt = 0; nt < 4; ++nt) {
            int col = n0 + nt * 16 + frow;
            if (col >= N) continue;
            float bv = bias ? bias[col] : 0.f;
            #pragma unroll
            for (int r = 0; r < 4; ++r) {
                int row = m0 + wv * 16 + fq * 4 + r;
                if (row >= M) continue;
                float v = accC[nt][r] + bv;
                if (relu) v = fmaxf(v, 0.f);
                if (outb) outb[(size_t)row * out_stride + col] = __float2bfloat16(clamp256(v));
                else      outf[(size_t)row * out_stride + col] = sane(v);
            }
        }
    } else {  // mode 2: register-resident LN + relu + residual
        // lane owns cols {n0 + nt*16 + frow} x rows {wv*16 + fq*4 + r}
        float bvc[4], bdc[4];
        #pragma unroll
        for (int nt = 0; nt < 4; ++nt) {
            int col = n0 + nt * 16 + frow;
            bvc[nt] = bias[col];
            bdc[nt] = (Wd && biasd) ? biasd[col] : 0.f;
        }
        float s[4], s2[4];
        #pragma unroll
        for (int nt = 0; nt < 4; ++nt) { s[nt] = 0.f; s2[nt] = 0.f; }
        #pragma unroll
        for (int nt = 0; nt < 4; ++nt)
            #pragma unroll
            for (int r = 0; r < 4; ++r) {
                int row = wv * 16 + fq * 4 + r;
                int l = row & 31;
                float v = sane(accC[nt][r] + bvc[nt]);
                if (l < nn) { s[nt] += v; s2[nt] += v * v; }
            }
        // reduce over the 4 fq quads (lanes frow, frow+16, +32, +48)
        #pragma unroll
        for (int nt = 0; nt < 4; ++nt) {
            s[nt]  += __shfl_xor(s[nt], 16);  s[nt]  += __shfl_xor(s[nt], 32);
            s2[nt] += __shfl_xor(s2[nt], 16); s2[nt] += __shfl_xor(s2[nt], 32);
        }
        if (fq == 0) {
            #pragma unroll
            for (int nt = 0; nt < 4; ++nt) {
                sS[wv][nt * 16 + frow]  = s[nt];
                sS2[wv][nt * 16 + frow] = s2[nt];
            }
        }
        __syncthreads();
        const int gi = wv >> 1;            // graph within tile (rows gi*32..gi*32+31)
        const float inv = 1.f / (float)nn;
        #pragma unroll
        for (int nt = 0; nt < 4; ++nt) {
            int c = nt * 16 + frow;
            int colg = n0 + c;
            float S  = sS[2 * gi][c]  + sS[2 * gi + 1][c];
            float S2 = sS2[2 * gi][c] + sS2[2 * gi + 1][c];
            float mu = S * inv;
            float var = S2 * inv - mu * mu;
            float rs = rsqrtf(fmaxf(var, 0.f) + 1e-5f);
            #pragma unroll
            for (int r = 0; r < 4; ++r) {
                int row = wv * 16 + fq * 4 + r;
                int l = row & 31;
                int grow = m0 + row;
                float outv = 0.f;
                if (l < nn) {
                    float v = (sane(accC[nt][r] + bvc[nt]) - mu) * rs * lnw[l] + lnb[l];
                    v = fmaxf(v, 0.f);
                    float rr = Wd ? sane(accR[nt][r] + bdc[nt])
                                  : __bfloat162float(res[(size_t)grow * res_stride + colg]);
                    outv = clamp256(v + rr);
                }
                outb[(size_t)grow * out_stride + colg] = __float2bfloat16(outv);
            }
        }
    }
}

// ---------------------------------------------------------------------------
// GAT edge scores: wave per edge; expe f32 in ws; f32 atomic denominator.
// ---------------------------------------------------------------------------
__global__ __launch_bounds__(256) void edge_kernel(
    const int* __restrict__ ei, const bf* __restrict__ xlb, const bf* __restrict__ xrb,
    const float* __restrict__ att, float* __restrict__ expe, float* __restrict__ nsum,
    int E0, int ET, int NN)
{
    int e = blockIdx.x * 4 + (threadIdx.x >> 6);
    if (e >= ET) return;
    int lane = threadIdx.x & 63;
    int src, dst;
    if (e < E0) { src = ei[e]; dst = ei[E0 + e]; }
    else        { src = dst = e - E0; }
    src = min(max(src, 0), NN - 1);
    dst = min(max(dst, 0), NN - 1);
    const bf* xls = xlb + (size_t)src * 256;
    const bf* xrd = xrb + (size_t)dst * 256;
    float s[4];
    #pragma unroll
    for (int h = 0; h < 4; ++h) {
        float v = __bfloat162float(xls[h * 64 + lane]) + __bfloat162float(xrd[h * 64 + lane]);
        v = v > 0.f ? v : 0.2f * v;
        s[h] = v * att[h * 64 + lane];
    }
    #pragma unroll
    for (int h = 0; h < 4; ++h)
        #pragma unroll
        for (int off = 32; off > 0; off >>= 1) s[h] += __shfl_down(s[h], off);
    if (lane == 0) {
        #pragma unroll
        for (int h = 0; h < 4; ++h) {
            float sv = fminf(fmaxf(s[h], -60.f), 60.f);   // sanitizes NaN too
            float ex = __expf(sv);
            expe[(size_t)e * 4 + h] = ex;
            atomicAdd(&nsum[(size_t)dst * 4 + h], ex);
        }
    }
}

// ---------------------------------------------------------------------------
// Per-graph aggregation: column-private LDS accumulators (no atomics/syncs).
// ---------------------------------------------------------------------------
__global__ __launch_bounds__(256) void agg_kernel(
    const int* __restrict__ ei, const bf* __restrict__ xlb,
    const float* __restrict__ expe, const float* __restrict__ nsum,
    const float* __restrict__ gbias, bf* __restrict__ hbuf,
    int E0, int EPG, int NN, int nn)
{
    __shared__ float accS[32 * 256];
    int g = blockIdx.x, ch = threadIdx.x, h = ch >> 6;
    for (int l = 0; l < nn; ++l) accS[l * 256 + ch] = 0.f;
    for (int j = 0; j < EPG; ++j) {
        int e = g * EPG + j;
        int src = min(max(ei[e], 0), NN - 1);
        int dst = min(max(ei[E0 + e], 0), NN - 1);
        int dl = min(max(dst - g * nn, 0), nn - 1);
        float al = expe[(size_t)e * 4 + h] / fmaxf(nsum[(size_t)dst * 4 + h], 1e-30f);
        al = fminf(fmaxf(al, 0.f), 1.f);
        accS[dl * 256 + ch] += al * __bfloat162float(xlb[(size_t)src * 256 + ch]);
    }
    for (int i = 0; i < nn; ++i) {
        int e = E0 + g * nn + i;
        int node = g * nn + i;
        float al = expe[(size_t)e * 4 + h] / fmaxf(nsum[(size_t)node * 4 + h], 1e-30f);
        al = fminf(fmaxf(al, 0.f), 1.f);
        accS[i * 256 + ch] += al * __bfloat162float(xlb[(size_t)node * 256 + ch]);
    }
    float bv = gbias[ch];
    for (int l = 0; l < nn; ++l) {
        float v = fmaxf(accS[l * 256 + ch] + bv, 0.f);
        hbuf[((size_t)g * 32 + l) * 256 + ch] = __float2bfloat16(clamp256(v));
    }
    for (int l = nn; l < 32; ++l)
        hbuf[((size_t)g * 32 + l) * 256 + ch] = __float2bfloat16(0.f);
}

// ---------------------------------------------------------------------------
// LAST kernel: alpha = expe/nsum (f32) and ei (f32 of exact indices).
// ---------------------------------------------------------------------------
__global__ __launch_bounds__(256) void alpha_ei_kernel(
    const int* __restrict__ ei, const float* __restrict__ expe,
    const float* __restrict__ nsum,
    float* __restrict__ dalpha, float* __restrict__ dei, int E0, int ET, int NN)
{
    int e = blockIdx.x * 256 + threadIdx.x;
    if (e >= ET) return;
    int src, dst;
    if (e < E0) { src = ei[e]; dst = ei[E0 + e]; }
    else        { src = dst = e - E0; }
    src = min(max(src, 0), NN - 1);
    dst = min(max(dst, 0), NN - 1);
    #pragma unroll
    for (int h = 0; h < 4; ++h) {
        float al = expe[(size_t)e * 4 + h] / fmaxf(nsum[(size_t)dst * 4 + h], 1e-30f);
        dalpha[(size_t)e * 4 + h] = fminf(fmaxf(al, 0.f), 1.f);
    }
    dei[e]              = (float)src;
    dei[(size_t)ET + e] = (float)dst;
}

// f32 -> bf16 bulk convert
__global__ void cvt_bf16(const float* __restrict__ in, bf* __restrict__ o, int n)
{
    int i = blockIdx.x * 256 + threadIdx.x;
    if (i < n) o[i] = __float2bfloat16(in[i]);
}

// Weight prep: f32 [Co][Ci][3] -> bf16 [3][Co][Ci]
__global__ void prep_taps(const float* __restrict__ w, bf* __restrict__ o, int Co, int Ci)
{
    int idx = blockIdx.x * 256 + threadIdx.x;
    if (idx >= Co * Ci) return;
    #pragma unroll
    for (int k = 0; k < 3; ++k)
        o[(size_t)k * Co * Ci + idx] = __float2bfloat16(w[(size_t)idx * 3 + k]);
}

// fc1_w f32 [F1][ci*nn+l] -> bf16 W1t [F1][l*256+ci], l padded to 32 with zeros
__global__ void prep_fc1(const float* __restrict__ w, bf* __restrict__ o, int F1, int nn)
{
    int idx = blockIdx.x * 256 + threadIdx.x;
    if (idx >= F1 * 8192) return;
    int co = idx >> 13, r = idx & 8191, l = r >> 8, ci = r & 255;
    float hv = 0.f;
    if (l < nn) hv = w[(size_t)co * (256 * nn) + ci * nn + l];
    o[idx] = __float2bfloat16(hv);
}

extern "C" void kernel_launch(void* const* d_in, const int* in_sizes, int n_in,
                              void* d_out, int out_size, void* d_ws, size_t ws_size,
                              hipStream_t stream)
{
    (void)n_in; (void)ws_size;
    // ALL float inputs are FLOAT32 (reference setup_inputs dtype); edge_index int32.
    const float* x   = (const float*)d_in[0];
    const float* Wl  = (const float*)d_in[1];  const float* bl  = (const float*)d_in[2];
    const float* Wr  = (const float*)d_in[3];  const float* br  = (const float*)d_in[4];
    const float* att = (const float*)d_in[5];  const float* gb  = (const float*)d_in[6];
    const float* t0w = (const float*)d_in[7];  const float* t0b = (const float*)d_in[8];
    const float* l0w = (const float*)d_in[9];  const float* l0b = (const float*)d_in[10];
    const float* t1w = (const float*)d_in[11]; const float* t1b = (const float*)d_in[12];
    const float* l1w = (const float*)d_in[13]; const float* l1b = (const float*)d_in[14];
    const float* d1w = (const float*)d_in[15]; const float* d1b = (const float*)d_in[16];
    const float* t2w = (const float*)d_in[17]; const float* t2b = (const float*)d_in[18];
    const float* l2w = (const float*)d_in[19]; const float* l2b = (const float*)d_in[20];
    const float* d2w = (const float*)d_in[21]; const float* d2b = (const float*)d_in[22];
    const float* f1w = (const float*)d_in[23]; const float* f1b = (const float*)d_in[24];
    const float* f2w = (const float*)d_in[25]; const float* f2b = (const float*)d_in[26];
    const float* f3w = (const float*)d_in[27]; const float* f3b = (const float*)d_in[28];
    const int*   ei  = (const int*)d_in[29];

    // ---- Runtime-derived shapes ----
    const int HC   = in_sizes[6];                        // 256
    const int F_IN = in_sizes[1] / (HC > 0 ? HC : 1);    // 64
    const int NN   = in_sizes[0] / (F_IN > 0 ? F_IN : 1);// 30720 nodes
    const int E0   = in_sizes[29] / 2;                   // 245760
    const int ET   = E0 + NN;                            // 276480
    int nn = in_sizes[9];  nn = nn < 1 ? 1 : (nn > 32 ? 32 : nn);  // 30
    const int NG   = NN / nn;                            // 1024
    const int EPG  = NG > 0 ? E0 / NG : 0;               // 240
    const int C1   = in_sizes[12];                       // 512
    const int C2   = in_sizes[18];                       // 256
    const int F1   = in_sizes[24];                       // 512
    const int F2   = in_sizes[26];                       // 256
    const int F3   = in_sizes[28];                       // 144
    const int NG2  = (NG + 1) / 2;

    // ---- Output layout (FLOAT32 elements), ei anchored at the end ----
    float* dout   = (float*)d_out;
    float* dei    = dout + ((size_t)out_size - 2 * (size_t)ET);
    float* dalpha = dei - (size_t)ET * 4;

    // ---- Workspace (peak ~40.5 MiB) ----
    char* ws = (char*)d_ws;
    const size_t MB = 1ull << 20;
    float* nsum = (float*)(ws);                               // [0, 0.5M)
    bf*    xb   = (bf*)(ws + 524288);                         // x bf16, 3.93M
    float* expe = (float*)(ws + 524288);                      // AFTER GAT GEMMs, 4.42M
    bf*    WkA  = (bf*)(ws + 5 * MB);                         // 3*HC*HC bf16
    bf*    WkB  = WkA + (size_t)3 * HC * HC;                  // 3*C1*HC
    bf*    WkC  = WkB + (size_t)3 * C1 * HC;                  // 3*C2*C1
    bf*    Wlb  = WkC + (size_t)3 * C2 * C1;
    bf*    Wrb  = Wlb + (size_t)HC * F_IN;
    bf*    f2wb = Wrb + (size_t)HC * F_IN;
    bf*    f3wb = f2wb + (size_t)F2 * F1;
    bf*    d1wb = f3wb + (size_t)F3 * F2;
    bf*    d2wb = d1wb + (size_t)C1 * HC;                     // ends < 8.5M
    const size_t S0 = (size_t)(8.5 * MB);
    const size_t S1 = S0 + 16 * MB;                           // total 40.5M
    bf*    xrb  = (bf*)(ws + S0);
    bf*    hbuf = (bf*)(ws + S0);
    bf*    y1c  = (bf*)(ws + S0);
    bf*    W1t  = (bf*)(ws + S0);
    bf*    z1   = (bf*)(ws + S0 + 9 * MB);
    bf*    z2   = (bf*)(ws + S0 + 11 * MB);
    bf*    xlb  = (bf*)(ws + S1);
    bf*    y0   = (bf*)(ws + S1);
    bf*    y2   = (bf*)(ws + S1);

    hipMemsetAsync(nsum, 0, (size_t)NN * 4 * sizeof(float), stream);

    // ---- Convert weights/inputs to bf16 ----
    cvt_bf16<<<(NN * F_IN + 255) / 256, 256, 0, stream>>>(x, xb, NN * F_IN);
    cvt_bf16<<<(HC * F_IN + 255) / 256, 256, 0, stream>>>(Wl, Wlb, HC * F_IN);
    cvt_bf16<<<(HC * F_IN + 255) / 256, 256, 0, stream>>>(Wr, Wrb, HC * F_IN);
    cvt_bf16<<<(F2 * F1 + 255) / 256, 256, 0, stream>>>(f2w, f2wb, F2 * F1);
    cvt_bf16<<<(F3 * F2 + 255) / 256, 256, 0, stream>>>(f3w, f3wb, F3 * F2);
    cvt_bf16<<<(C1 * HC + 255) / 256, 256, 0, stream>>>(d1w, d1wb, C1 * HC);
    cvt_bf16<<<(C2 * C1 + 255) / 256, 256, 0, stream>>>(d2w, d2wb, C2 * C1);
    prep_taps<<<(HC * HC + 255) / 256, 256, 0, stream>>>(t0w, WkA, HC, HC);
    prep_taps<<<(C1 * HC + 255) / 256, 256, 0, stream>>>(t1w, WkB, C1, HC);
    prep_taps<<<(C2 * C1 + 255) / 256, 256, 0, stream>>>(t2w, WkC, C2, C1);

    // ---- GAT linear transforms (bf16 out) ----
    gemm_kernel<<<dim3((HC + 63) / 64, (NN + 63) / 64), 256, 0, stream>>>(
        xb, Wlb, nullptr, bl, nullptr, nullptr, nullptr, nullptr, 0,
        xlb, nullptr, HC, NN, HC, F_IN, 1, 1, 0, 0, 0, nn);
    gemm_kernel<<<dim3((HC + 63) / 64, (NN + 63) / 64), 256, 0, stream>>>(
        xb, Wrb, nullptr, br, nullptr, nullptr, nullptr, nullptr, 0,
        xrb, nullptr, HC, NN, HC, F_IN, 1, 1, 0, 0, 0, nn);

    // ---- Edge scores + aggregation ----
    edge_kernel<<<(ET + 3) / 4, 256, 0, stream>>>(ei, xlb, xrb, att, expe, nsum, E0, ET, NN);
    agg_kernel<<<NG, 256, 0, stream>>>(ei, xlb, expe, nsum, gb, hbuf, E0, EPG, NN, nn);

    // ---- TCN block 0 (full): conv(d=1) -> LN -> relu -> + h ----
    gemm_kernel<<<dim3((HC + 63) / 64, NG * 32 / 64), 256, 0, stream>>>(
        hbuf, WkA, nullptr, t0b, nullptr, l0w, l0b, hbuf, HC,
        y0, nullptr, HC, NG * 32, HC, HC, 3, 1, 2, 0, 1, nn);

    // ---- TCN blocks 1 & 2, two graph-chunks; y2 in place over y0 ----
    for (int c = 0; c < 2; ++c) {
        int g0 = c * NG2;
        int gc = (c == 0) ? NG2 : (NG - NG2);
        if (gc <= 0) continue;
        const bf* y0c = y0 + (size_t)g0 * 32 * HC;
        bf*       y2c = y0 + (size_t)g0 * 32 * HC;
        gemm_kernel<<<dim3((C1 + 63) / 64, gc * 32 / 64), 256, 0, stream>>>(
            y0c, WkB, d1wb, t1b, d1b, l1w, l1b, nullptr, 0,
            y1c, nullptr, C1, gc * 32, C1, HC, 3, 2, 2, 0, 1, nn);
        gemm_kernel<<<dim3((C2 + 63) / 64, gc * 32 / 64), 256, 0, stream>>>(
            y1c, WkC, d2wb, t2b, d2b, l2w, l2b, nullptr, 0,
            y2c, nullptr, C2, gc * 32, C2, C1, 3, 4, 2, 0, 1, nn);
    }

    // ---- FC head (W1t overwrites dead y1c) ----
    prep_fc1<<<(F1 * 8192 + 255) / 256, 256, 0, stream>>>(f1w, W1t, F1, nn);
    gemm_kernel<<<dim3((F1 + 63) / 64, (NG + 63) / 64), 256, 0, stream>>>(
        y2, W1t, nullptr, f1b, nullptr, nullptr, nullptr, nullptr, 0,
        z1, nullptr, F1, NG, F1, 8192, 1, 1, 0, 1, 0, nn);
    gemm_kernel<<<dim3((F2 + 63) / 64, (NG + 63) / 64), 256, 0, stream>>>(
        z1, f2wb, nullptr, f2b, nullptr, nullptr, nullptr, nullptr, 0,
        z2, nullptr, F2, NG, F2, F1, 1, 1, 0, 1, 0, nn);
    gemm_kernel<<<dim3((F3 + 63) / 64, (NG + 63) / 64), 256, 0, stream>>>(
        z2, f3wb, nullptr, f3b, nullptr, nullptr, nullptr, nullptr, 0,
        nullptr, dout, F3, NG, F3, F2, 1, 1, 0, 0, 0, nn);

    // ---- LAST: alpha (f32) + ei (f32) ----
    alpha_ei_kernel<<<(ET + 255) / 256, 256, 0, stream>>>(
        ei, expe, nsum, dalpha, dei, E0, ET, NN);
}